// Round 16
// baseline (202.616 us; speedup 1.0000x reference)
//
#include <hip/hip_runtime.h>

typedef float f32x4 __attribute__((ext_vector_type(4)));
typedef __bf16 bf16x8 __attribute__((ext_vector_type(8)));
typedef __bf16 bf16x4 __attribute__((ext_vector_type(4)));

#define B_ 4
#define T_ 2048
#define D_ 1024
#define H_ 16
#define HD_ 64

__device__ __forceinline__ void gload_lds16(const void* g, void* l) {
  __builtin_amdgcn_global_load_lds(
      (const __attribute__((address_space(1))) void*)g,
      (__attribute__((address_space(3))) void*)l, 16, 0, 0);
}

// ---------------------------------------------------------------- convert x
__global__ __launch_bounds__(256) void k_cvt_f32_bf16(
    const float* __restrict__ in, __bf16* __restrict__ out, int n4) {
  int i = blockIdx.x * blockDim.x + threadIdx.x;
  int stride = gridDim.x * blockDim.x;
  for (; i < n4; i += stride) {
    float4 v = reinterpret_cast<const float4*>(in)[i];
    bf16x4 o = { (__bf16)v.x, (__bf16)v.y, (__bf16)v.z, (__bf16)v.w };
    reinterpret_cast<bf16x4*>(out)[i] = o;
  }
}

// ------------------------------------------- transpose (+convert) to bf16
template <typename Tin>
__global__ __launch_bounds__(256) void k_transpose_bf16(
    const Tin* __restrict__ in, __bf16* __restrict__ out,
    int R, int C, long inb, long outb) {
  __shared__ alignas(16) __bf16 lds[64 * 68];
  const int t = threadIdx.x;
  in  += (long)blockIdx.z * inb;
  out += (long)blockIdx.z * outb;
  const int r0 = blockIdx.y * 64, c0 = blockIdx.x * 64;
#pragma unroll
  for (int i = 0; i < 16; ++i) {
    int e = i * 256 + t, row = e >> 6, col = e & 63;
    lds[row * 68 + col] = (__bf16)(float)in[(long)(r0 + row) * C + c0 + col];
  }
  __syncthreads();
#pragma unroll
  for (int i = 0; i < 16; ++i) {
    int e = i * 256 + t, orow = e >> 6, ocol = e & 63;
    out[(long)(c0 + orow) * R + r0 + ocol] = lds[ocol * 68 + orow];
  }
}

// ---------------------------------------------------------------- GEMM (bt)
// 128x128 tile, BK=32, 3-ring counted-vmcnt staging (round 15).
// NEW (round 16): OPERAND-SWAPPED MFMA for q/k and proj outputs.
// mfma(X,Y): col(lane&15) indexes Y's rows, reg indexes X's rows. Swapping
// to mfma(bfr, af) puts the register axis along n (hd) -> the 4 reg values
// are 4 CONSECUTIVE output elements -> packed bf16x4/float4 stores
// (16 store insts/thread instead of 64 scattered 2B/4B stores). The
// scattered epilogue is the common bottleneck of all four K-loop schedules
// tried (all plateau at ~610 TF with <20% of any pipe saturated).
// v output keeps unswapped order (wants tt-consecutive, already packed).
template <int EPI>
__global__ __launch_bounds__(256) void k_gemm_bt(
    const __bf16* __restrict__ A, const __bf16* __restrict__ Bt,
    const float* __restrict__ bias, void* __restrict__ Cout,
    __bf16* __restrict__ vout, int M, int N, int K) {
  __shared__ alignas(16) __bf16 As[3][128 * 32];
  __shared__ alignas(16) __bf16 Bs[3][128 * 32];
  const int t = threadIdx.x;
  const int w = t >> 6, l = t & 63;
  const int g = l >> 4, r16 = l & 15;
  const int wr = w >> 1, wc = w & 1;
  const int m0 = blockIdx.y * 128, n0 = blockIdx.x * 128;
  // swap: q/k blocks (EPI 0, n0 < 2048) and all proj blocks (EPI 1).
  const bool swp = (EPI == 1) || (n0 < 2048);

  f32x4 acc[4][4];
#pragma unroll
  for (int i = 0; i < 4; ++i)
#pragma unroll
    for (int j = 0; j < 4; ++j) acc[i][j] = (f32x4){0.f, 0.f, 0.f, 0.f};

  const int arow = t >> 2;                                  // 0..63
  const int acol = ((t & 3) ^ ((t >> 3) & 3)) * 8;          // pre-swizzled src
  const char* Ag = (const char*)(A + (long)(m0 + arow) * K + acol);
  const char* Bg = (const char*)(Bt + (long)(n0 + arow) * K + acol);
  const long rowskip = (long)64 * K * 2;
  const int rdsw = (g ^ ((r16 >> 1) & 3)) * 8;              // read-side slot

  auto stage = [&](int buf, int ktile) {
    const long koff = (long)ktile * 64;                     // 32 cols * 2B
    char* AsW = (char*)As[buf] + w * 1024;
    char* BsW = (char*)Bs[buf] + w * 1024;
    gload_lds16(Ag + koff, AsW);
    gload_lds16(Ag + koff + rowskip, AsW + 4096);
    gload_lds16(Bg + koff, BsW);
    gload_lds16(Bg + koff + rowskip, BsW + 4096);
  };

  const int NT = K >> 5;                 // K-tiles
  stage(0, 0);                           // prologue: 2-tile lead
  stage(1, 1);

  for (int kt = 0; kt < NT; ++kt) {
    asm volatile("s_waitcnt vmcnt(4)" ::: "memory");  // tile kt landed
    __builtin_amdgcn_sched_barrier(0);
    __builtin_amdgcn_s_barrier();        // publish kt; WAR for ring slot
    __builtin_amdgcn_sched_barrier(0);
    const int kn = (kt + 2 < NT) ? kt + 2 : NT - 1;   // tail: dummy re-stage
    stage((kt + 2) % 3, kn);
    const __bf16* Ab = As[kt % 3];
    const __bf16* Bb = Bs[kt % 3];
    bf16x8 af[4], bfr[4];
#pragma unroll
    for (int mi = 0; mi < 4; ++mi)
      af[mi] = *reinterpret_cast<const bf16x8*>(
          &Ab[(wr * 64 + mi * 16 + r16) * 32 + rdsw]);
#pragma unroll
    for (int ni = 0; ni < 4; ++ni)
      bfr[ni] = *reinterpret_cast<const bf16x8*>(
          &Bb[(wc * 64 + ni * 16 + r16) * 32 + rdsw]);
    __builtin_amdgcn_s_setprio(1);
    if (swp) {
#pragma unroll
      for (int mi = 0; mi < 4; ++mi)
#pragma unroll
        for (int ni = 0; ni < 4; ++ni)
          acc[mi][ni] = __builtin_amdgcn_mfma_f32_16x16x32_bf16(
              bfr[ni], af[mi], acc[mi][ni], 0, 0, 0);
    } else {
#pragma unroll
      for (int mi = 0; mi < 4; ++mi)
#pragma unroll
        for (int ni = 0; ni < 4; ++ni)
          acc[mi][ni] = __builtin_amdgcn_mfma_f32_16x16x32_bf16(
              af[mi], bfr[ni], acc[mi][ni], 0, 0, 0);
    }
    __builtin_amdgcn_s_setprio(0);
  }
  asm volatile("s_waitcnt vmcnt(0)" ::: "memory");  // drain dummies pre-exit

  if (EPI == 0) {
    const int which = n0 >> 10;          // block-uniform (128 | 1024)
    __bf16* qkvb = (__bf16*)Cout;
    if (which < 2) {
      // swapped layout: m = ...+r16 (lane), n = ...+g*4+reg (4 consecutive)
#pragma unroll
      for (int ni = 0; ni < 4; ++ni) {
        const int nb = n0 + wc * 64 + ni * 16 + g * 4;
        const float4 bv4 = *reinterpret_cast<const float4*>(&bias[nb]);
        const int h = (nb & 1023) >> 6, hd0 = nb & 63;
#pragma unroll
        for (int mi = 0; mi < 4; ++mi) {
          const int m = m0 + wr * 64 + mi * 16 + r16;
          const int b = m >> 11, tt = m & 2047;
          f32x4 c = acc[mi][ni];
          bf16x4 pk = { (__bf16)(c[0] + bv4.x), (__bf16)(c[1] + bv4.y),
                        (__bf16)(c[2] + bv4.z), (__bf16)(c[3] + bv4.w) };
          *reinterpret_cast<bf16x4*>(
              &qkvb[((long)((which * B_ + b) * H_ + h) * T_ + tt) * HD_ + hd0]) = pk;
        }
      }
    } else {
      // v: unswapped, packed along tt into [B][H][64][T]
#pragma unroll
      for (int mi = 0; mi < 4; ++mi) {
#pragma unroll
        for (int ni = 0; ni < 4; ++ni) {
          const int n = n0 + wc * 64 + ni * 16 + r16;
          const float bv = bias[n];
          f32x4 c = acc[mi][ni];
          const int rem = n & 1023, h = rem >> 6, hd = rem & 63;
          const int mbase = m0 + wr * 64 + mi * 16 + g * 4;
          const int b = mbase >> 11, tt0 = mbase & 2047;
          bf16x4 pk = { (__bf16)(c[0] + bv), (__bf16)(c[1] + bv),
                        (__bf16)(c[2] + bv), (__bf16)(c[3] + bv) };
          *reinterpret_cast<bf16x4*>(
              &vout[(((long)b * H_ + h) * HD_ + hd) * T_ + tt0]) = pk;
        }
      }
    }
  } else {
    // proj: swapped layout -> float4 packed stores along n
    float* O = (float*)Cout;
#pragma unroll
    for (int ni = 0; ni < 4; ++ni) {
      const int nb = n0 + wc * 64 + ni * 16 + g * 4;
      const float4 bv4 = *reinterpret_cast<const float4*>(&bias[nb]);
#pragma unroll
      for (int mi = 0; mi < 4; ++mi) {
        const int m = m0 + wr * 64 + mi * 16 + r16;
        f32x4 c = acc[mi][ni];
        float4 ov = { c[0] + bv4.x, c[1] + bv4.y, c[2] + bv4.z, c[3] + bv4.w };
        *reinterpret_cast<float4*>(&O[(long)m * N + nb]) = ov;
      }
    }
  }
}

// ---------------------------------------------------------------- attention
// Swapped-QK^T softmax, Q pre-scaled (log2-domain), no max tracking,
// raw v_exp_f32, in-register P via cvt_pk + permlane32/16 swaps.
__device__ __forceinline__ void soft_side(
    const f32x4 (&s)[4], float& lrun, bool diag, int qrel,
    int g, int r16, bf16x8& pa0, bf16x8& pa1) {
  float p[4][4];
#pragma unroll
  for (int nf = 0; nf < 4; ++nf) {
#pragma unroll
    for (int rr = 0; rr < 4; ++rr) {
      float x = s[nf][rr];
      if (diag) x = (nf * 16 + 4 * g + rr <= qrel + r16) ? x : -1e30f;
      p[nf][rr] = __builtin_amdgcn_exp2f(x);  // 2^-1e30 -> +0
    }
  }
  const float ps0 = (p[0][0] + p[0][1]) + (p[0][2] + p[0][3]);
  const float ps1 = (p[1][0] + p[1][1]) + (p[1][2] + p[1][3]);
  const float ps2 = (p[2][0] + p[2][1]) + (p[2][2] + p[2][3]);
  const float ps3 = (p[3][0] + p[3][1]) + (p[3][2] + p[3][3]);
  lrun += (ps0 + ps1) + (ps2 + ps3);

  unsigned u[4][2];
#pragma unroll
  for (int nf = 0; nf < 4; ++nf) {
    asm("v_cvt_pk_bf16_f32 %0, %1, %2"
        : "=v"(u[nf][0]) : "v"(p[nf][0]), "v"(p[nf][1]));
    asm("v_cvt_pk_bf16_f32 %0, %1, %2"
        : "=v"(u[nf][1]) : "v"(p[nf][2]), "v"(p[nf][3]));
  }
#pragma unroll
  for (int j = 0; j < 2; ++j) {
    asm("v_permlane32_swap_b32 %0, %1" : "+v"(u[0][j]), "+v"(u[1][j]));
    asm("v_permlane32_swap_b32 %0, %1" : "+v"(u[2][j]), "+v"(u[3][j]));
  }
#pragma unroll
  for (int j = 0; j < 2; ++j) {
    asm("v_permlane16_swap_b32 %0, %1" : "+v"(u[0][j]), "+v"(u[1][j]));
    asm("v_permlane16_swap_b32 %0, %1" : "+v"(u[2][j]), "+v"(u[3][j]));
  }
  union PU { unsigned w[4]; bf16x8 v; };
  PU a0, a1;
  a0.w[0] = u[0][0]; a0.w[1] = u[0][1]; a0.w[2] = u[1][0]; a0.w[3] = u[1][1];
  a1.w[0] = u[2][0]; a1.w[1] = u[2][1]; a1.w[2] = u[3][0]; a1.w[3] = u[3][1];
  pa0 = a0.v;
  pa1 = a1.v;
}

// PV operand-swapped (round 16): oacc = mfma(v_frag, pa) -> lane&15 = q,
// reg = 4 consecutive hd -> packed bf16x4 o-stores AND inv needs no
// broadcast shuffle (lane q = r16 owns lrun).
__global__ __launch_bounds__(256) void k_attn(
    const __bf16* __restrict__ q, const __bf16* __restrict__ k,
    const __bf16* __restrict__ vt, __bf16* __restrict__ o) {
  __shared__ alignas(16) __bf16 Ks[2][64 * 64];
  __shared__ alignas(16) __bf16 Vs[2][64 * 64];
  const int t = threadIdx.x, w = t >> 6, l = t & 63;
  const int g = l >> 4, r16 = l & 15;
  const int bh = blockIdx.x;
  const int qt = 31 - blockIdx.y;
  const int qbase = qt * 64 + w * 16;
  const float sc = 0.125f * 1.44269504088896341f;  // 1/sqrt(64) * log2(e)

  auto scale8 = [&](bf16x8 v) {
    bf16x8 r;
#pragma unroll
    for (int j = 0; j < 8; ++j) r[j] = (__bf16)((float)v[j] * sc);
    return r;
  };
  const __bf16* qp = q + ((long)bh * T_ + qbase + r16) * HD_ + g * 8;
  const bf16x8 aq0 = scale8(*reinterpret_cast<const bf16x8*>(qp));
  const bf16x8 aq1 = scale8(*reinterpret_cast<const bf16x8*>(qp + 32));

  f32x4 oacc[4];
  float lrun = 0.f;
#pragma unroll
  for (int i = 0; i < 4; ++i) oacc[i] = (f32x4){0.f, 0.f, 0.f, 0.f};

  const int srow = t >> 3, sslot = t & 7;
  const int sswz = sslot ^ (srow & 7);
  const char* kg = (const char*)(k + ((long)bh * T_ + srow) * HD_) + sswz * 16;
  const char* vg = (const char*)(vt + ((long)bh * HD_ + srow) * T_) + sswz * 16;

  auto stage = [&](int buf, int kv0) {
    char* Kd = (char*)Ks[buf] + w * 1024;
    char* Vd = (char*)Vs[buf] + w * 1024;
    gload_lds16(kg + (long)kv0 * 128, Kd);
    gload_lds16(kg + (long)kv0 * 128 + 32 * 128, Kd + 4096);
    gload_lds16(vg + (long)kv0 * 2, Vd);
    gload_lds16(vg + (long)kv0 * 2 + 32 * (long)T_ * 2, Vd + 4096);
  };

  stage(0, 0);
  __syncthreads();

  const int ntile = qt + 1;
  for (int it = 0; it < ntile; ++it) {
    const int cur = it & 1;
    if (it + 1 < ntile) stage(cur ^ 1, (it + 1) * 64);
    const char* Kc = (const char*)Ks[cur];
    const char* Vc = (const char*)Vs[cur];

    f32x4 s[4];
    __builtin_amdgcn_s_setprio(1);
#pragma unroll
    for (int nf = 0; nf < 4; ++nf) {
      const char* kb = Kc + (nf * 16 + r16) * 128;
      const bf16x8 b0 = *reinterpret_cast<const bf16x8*>(kb + ((g ^ (r16 & 7)) << 4));
      const bf16x8 b1 = *reinterpret_cast<const bf16x8*>(kb + (((4 + g) ^ (r16 & 7)) << 4));
      f32x4 z = (f32x4){0.f, 0.f, 0.f, 0.f};
      z = __builtin_amdgcn_mfma_f32_16x16x32_bf16(b0, aq0, z, 0, 0, 0);
      z = __builtin_amdgcn_mfma_f32_16x16x32_bf16(b1, aq1, z, 0, 0, 0);
      s[nf] = z;
    }
    __builtin_amdgcn_s_setprio(0);

    bf16x8 pa0, pa1;
    soft_side(s, lrun, it == qt, qbase - it * 64, g, r16, pa0, pa1);

    __builtin_amdgcn_s_setprio(1);
#pragma unroll
    for (int nf = 0; nf < 4; ++nf) {
      const char* vb = Vc + (nf * 16 + r16) * 128;
      const bf16x8 v0 = *reinterpret_cast<const bf16x8*>(vb + ((g ^ (r16 & 7)) << 4));
      const bf16x8 v1 = *reinterpret_cast<const bf16x8*>(vb + (((4 + g) ^ (r16 & 7)) << 4));
      oacc[nf] = __builtin_amdgcn_mfma_f32_16x16x32_bf16(v0, pa0, oacc[nf], 0, 0, 0);
      oacc[nf] = __builtin_amdgcn_mfma_f32_16x16x32_bf16(v1, pa1, oacc[nf], 0, 0, 0);
    }
    __builtin_amdgcn_s_setprio(0);
    __syncthreads();
  }

  // lrun partials are per g-group -> fold over g, then lane q=r16 owns it.
  lrun += __shfl_xor(lrun, 16, 64);
  lrun += __shfl_xor(lrun, 32, 64);
  const float inv = 1.f / lrun;
  const int b = bh >> 4, h = bh & 15;
  const int tt = qbase + r16;
#pragma unroll
  for (int nf = 0; nf < 4; ++nf) {
    const int hd0 = nf * 16 + g * 4;
    bf16x4 pk = { (__bf16)(oacc[nf][0] * inv), (__bf16)(oacc[nf][1] * inv),
                  (__bf16)(oacc[nf][2] * inv), (__bf16)(oacc[nf][3] * inv) };
    *reinterpret_cast<bf16x4*>(
        &o[((long)b * T_ + tt) * D_ + h * HD_ + hd0]) = pk;
  }
}

// ---------------------------------------------------------------- launcher
extern "C" void kernel_launch(void* const* d_in, const int* in_sizes, int n_in,
                              void* d_out, int out_size, void* d_ws, size_t ws_size,
                              hipStream_t stream) {
  (void)in_sizes; (void)n_in; (void)out_size; (void)ws_size;
  const float* x     = (const float*)d_in[0];
  const float* Wqkv  = (const float*)d_in[1];
  const float* bqkv  = (const float*)d_in[2];
  const float* Wproj = (const float*)d_in[3];
  const float* bproj = (const float*)d_in[4];
  float* out = (float*)d_out;

  const long MT = (long)B_ * T_;          // 8192
  __bf16* xb     = (__bf16*)d_ws;                    // [8192][1024]
  __bf16* wqkvt  = xb + MT * D_;                     // [3072][1024]
  __bf16* wprojt = wqkvt + (long)3 * D_ * D_;        // [1024][1024]
  __bf16* qkvb   = wprojt + (long)D_ * D_;           // q,k: [2][B][H][T][64]
  __bf16* vtb    = qkvb + (long)2 * B_ * H_ * T_ * HD_;  // [B][H][64][T]
  __bf16* attno  = vtb + (long)B_ * H_ * HD_ * T_;   // [8192][1024]

  k_cvt_f32_bf16<<<2048, 256, 0, stream>>>(x, xb, (int)(MT * D_ / 4));
  k_transpose_bf16<float><<<dim3(48, 16, 1), 256, 0, stream>>>(Wqkv, wqkvt, D_, 3 * D_, 0, 0);
  k_transpose_bf16<float><<<dim3(16, 16, 1), 256, 0, stream>>>(Wproj, wprojt, D_, D_, 0, 0);
  k_gemm_bt<0><<<dim3(24, 64), 256, 0, stream>>>(xb, wqkvt, bqkv, qkvb, vtb, 8192, 3072, 1024);
  k_attn<<<dim3(64, 32), 256, 0, stream>>>(
      qkvb, qkvb + (long)B_ * H_ * T_ * HD_, vtb, attno);
  k_gemm_bt<1><<<dim3(8, 64), 256, 0, stream>>>(attno, wprojt, bproj, out, nullptr, 8192, 1024, 1024);
}

// Round 17
// 164.203 us; speedup vs baseline: 1.2339x; 1.2339x over previous
//
#include <hip/hip_runtime.h>

typedef float f32x4 __attribute__((ext_vector_type(4)));
typedef __bf16 bf16x8 __attribute__((ext_vector_type(8)));
typedef __bf16 bf16x4 __attribute__((ext_vector_type(4)));

#define B_ 4
#define T_ 2048
#define D_ 1024
#define H_ 16
#define HD_ 64

__device__ __forceinline__ void gload_lds16(const void* g, void* l) {
  __builtin_amdgcn_global_load_lds(
      (const __attribute__((address_space(1))) void*)g,
      (__attribute__((address_space(3))) void*)l, 16, 0, 0);
}

// ---------------------------------------------------------------- convert x
__global__ __launch_bounds__(256) void k_cvt_f32_bf16(
    const float* __restrict__ in, __bf16* __restrict__ out, int n4) {
  int i = blockIdx.x * blockDim.x + threadIdx.x;
  int stride = gridDim.x * blockDim.x;
  for (; i < n4; i += stride) {
    float4 v = reinterpret_cast<const float4*>(in)[i];
    bf16x4 o = { (__bf16)v.x, (__bf16)v.y, (__bf16)v.z, (__bf16)v.w };
    reinterpret_cast<bf16x4*>(out)[i] = o;
  }
}

// ------------------------------------------- transpose (+convert) to bf16
template <typename Tin>
__global__ __launch_bounds__(256) void k_transpose_bf16(
    const Tin* __restrict__ in, __bf16* __restrict__ out,
    int R, int C, long inb, long outb) {
  __shared__ alignas(16) __bf16 lds[64 * 68];
  const int t = threadIdx.x;
  in  += (long)blockIdx.z * inb;
  out += (long)blockIdx.z * outb;
  const int r0 = blockIdx.y * 64, c0 = blockIdx.x * 64;
#pragma unroll
  for (int i = 0; i < 16; ++i) {
    int e = i * 256 + t, row = e >> 6, col = e & 63;
    lds[row * 68 + col] = (__bf16)(float)in[(long)(r0 + row) * C + c0 + col];
  }
  __syncthreads();
#pragma unroll
  for (int i = 0; i < 16; ++i) {
    int e = i * 256 + t, orow = e >> 6, ocol = e & 63;
    out[(long)(c0 + orow) * R + r0 + ocol] = lds[ocol * 68 + orow];
  }
}

// ---------------------------------------------------------------- GEMM (bt)
// 128x128 tile, BK=32, 256 thr, double-buffered LDS, 2-phase overlap,
// XOR-swizzled LDS (pre-swizzled global source + XOR'd read slot).
// ROUND-16 LESSON: do NOT operand-swap the MFMA for packed epilogue
// stores -- it perturbs main-loop codegen (VALUBusy 20->48%, -37us).
// Scattered epilogue stores are NOT the bottleneck.
template <int EPI>
__global__ __launch_bounds__(256) void k_gemm_bt(
    const __bf16* __restrict__ A, const __bf16* __restrict__ Bt,
    const float* __restrict__ bias, void* __restrict__ Cout,
    __bf16* __restrict__ vout, int M, int N, int K) {
  __shared__ alignas(16) __bf16 As[2][128 * 32];
  __shared__ alignas(16) __bf16 Bs[2][128 * 32];
  const int t = threadIdx.x;
  const int w = t >> 6, l = t & 63;
  const int g = l >> 4, r16 = l & 15;
  const int wr = w >> 1, wc = w & 1;
  const int m0 = blockIdx.y * 128, n0 = blockIdx.x * 128;

  f32x4 acc[4][4];
#pragma unroll
  for (int i = 0; i < 4; ++i)
#pragma unroll
    for (int j = 0; j < 4; ++j) acc[i][j] = (f32x4){0.f, 0.f, 0.f, 0.f};

  const int arow = t >> 2;                                  // 0..63
  const int acol = ((t & 3) ^ ((t >> 3) & 3)) * 8;          // pre-swizzled src
  const char* Ag = (const char*)(A + (long)(m0 + arow) * K + acol);
  const char* Bg = (const char*)(Bt + (long)(n0 + arow) * K + acol);
  const long rowskip = (long)64 * K * 2;
  const int rdsw = (g ^ ((r16 >> 1) & 3)) * 8;              // read-side slot

  auto stage = [&](int buf, long koff) {
    char* AsW = (char*)As[buf] + w * 1024;
    char* BsW = (char*)Bs[buf] + w * 1024;
    gload_lds16(Ag + koff, AsW);
    gload_lds16(Ag + koff + rowskip, AsW + 4096);
    gload_lds16(Bg + koff, BsW);
    gload_lds16(Bg + koff + rowskip, BsW + 4096);
  };

  stage(0, 0);
  __syncthreads();

  for (int kt = 0; kt < K; kt += 32) {
    const int cur = (kt >> 5) & 1;
    if (kt + 32 < K) stage(cur ^ 1, (long)(kt + 32) * 2);
    bf16x8 af[4], bfr[4];
#pragma unroll
    for (int mi = 0; mi < 4; ++mi)
      af[mi] = *reinterpret_cast<const bf16x8*>(
          &As[cur][(wr * 64 + mi * 16 + r16) * 32 + rdsw]);
#pragma unroll
    for (int ni = 0; ni < 4; ++ni)
      bfr[ni] = *reinterpret_cast<const bf16x8*>(
          &Bs[cur][(wc * 64 + ni * 16 + r16) * 32 + rdsw]);
    __builtin_amdgcn_s_setprio(1);
#pragma unroll
    for (int mi = 0; mi < 4; ++mi)
#pragma unroll
      for (int ni = 0; ni < 4; ++ni)
        acc[mi][ni] = __builtin_amdgcn_mfma_f32_16x16x32_bf16(af[mi], bfr[ni], acc[mi][ni], 0, 0, 0);
    __builtin_amdgcn_s_setprio(0);
    __syncthreads();
  }

  if (EPI == 0) {
    const int which = n0 >> 10;
    __bf16* qkvb = (__bf16*)Cout;
#pragma unroll
    for (int mi = 0; mi < 4; ++mi) {
#pragma unroll
      for (int ni = 0; ni < 4; ++ni) {
        const int n = n0 + wc * 64 + ni * 16 + r16;
        const float bv = bias[n];
        f32x4 c = acc[mi][ni];
        const int rem = n & 1023, h = rem >> 6, hd = rem & 63;
        const int mbase = m0 + wr * 64 + mi * 16 + g * 4;
        const int b = mbase >> 11, tt0 = mbase & 2047;
        if (which < 2) {
#pragma unroll
          for (int r = 0; r < 4; ++r)
            qkvb[((long)((which * B_ + b) * H_ + h) * T_ + tt0 + r) * HD_ + hd] =
                (__bf16)(c[r] + bv);
        } else {
          bf16x4 pk = { (__bf16)(c[0] + bv), (__bf16)(c[1] + bv),
                        (__bf16)(c[2] + bv), (__bf16)(c[3] + bv) };
          *reinterpret_cast<bf16x4*>(
              &vout[(((long)b * H_ + h) * HD_ + hd) * T_ + tt0]) = pk;
        }
      }
    }
  } else {
    float* O = (float*)Cout;
#pragma unroll
    for (int mi = 0; mi < 4; ++mi) {
#pragma unroll
      for (int ni = 0; ni < 4; ++ni) {
        const int n = n0 + wc * 64 + ni * 16 + r16;
        const float bv = bias[n];
        f32x4 c = acc[mi][ni];
        const int mbase = m0 + wr * 64 + mi * 16 + g * 4;
#pragma unroll
        for (int r = 0; r < 4; ++r) O[(long)(mbase + r) * N + n] = c[r] + bv;
      }
    }
  }
}

// ---------------------------------------------------------------- attention
// Swapped-QK^T softmax, Q pre-scaled (log2-domain), no max tracking,
// raw v_exp_f32, in-register P via cvt_pk + permlane32/16 swaps.
__device__ __forceinline__ void soft_side(
    const f32x4 (&s)[4], float& lrun, bool diag, int qrel,
    int g, int r16, bf16x8& pa0, bf16x8& pa1) {
  float p[4][4];
#pragma unroll
  for (int nf = 0; nf < 4; ++nf) {
#pragma unroll
    for (int rr = 0; rr < 4; ++rr) {
      float x = s[nf][rr];
      if (diag) x = (nf * 16 + 4 * g + rr <= qrel + r16) ? x : -1e30f;
      p[nf][rr] = __builtin_amdgcn_exp2f(x);  // 2^-1e30 -> +0
    }
  }
  const float ps0 = (p[0][0] + p[0][1]) + (p[0][2] + p[0][3]);
  const float ps1 = (p[1][0] + p[1][1]) + (p[1][2] + p[1][3]);
  const float ps2 = (p[2][0] + p[2][1]) + (p[2][2] + p[2][3]);
  const float ps3 = (p[3][0] + p[3][1]) + (p[3][2] + p[3][3]);
  lrun += (ps0 + ps1) + (ps2 + ps3);

  unsigned u[4][2];
#pragma unroll
  for (int nf = 0; nf < 4; ++nf) {
    asm("v_cvt_pk_bf16_f32 %0, %1, %2"
        : "=v"(u[nf][0]) : "v"(p[nf][0]), "v"(p[nf][1]));
    asm("v_cvt_pk_bf16_f32 %0, %1, %2"
        : "=v"(u[nf][1]) : "v"(p[nf][2]), "v"(p[nf][3]));
  }
#pragma unroll
  for (int j = 0; j < 2; ++j) {
    asm("v_permlane32_swap_b32 %0, %1" : "+v"(u[0][j]), "+v"(u[1][j]));
    asm("v_permlane32_swap_b32 %0, %1" : "+v"(u[2][j]), "+v"(u[3][j]));
  }
#pragma unroll
  for (int j = 0; j < 2; ++j) {
    asm("v_permlane16_swap_b32 %0, %1" : "+v"(u[0][j]), "+v"(u[1][j]));
    asm("v_permlane16_swap_b32 %0, %1" : "+v"(u[2][j]), "+v"(u[3][j]));
  }
  union PU { unsigned w[4]; bf16x8 v; };
  PU a0, a1;
  a0.w[0] = u[0][0]; a0.w[1] = u[0][1]; a0.w[2] = u[1][0]; a0.w[3] = u[1][1];
  a1.w[0] = u[2][0]; a1.w[1] = u[2][1]; a1.w[2] = u[3][0]; a1.w[3] = u[3][1];
  pa0 = a0.v;
  pa1 = a1.v;
}

// UNPAIRED: one block = one 64-row q-tile. grid (bh=64, y=32), qt=31-y
// (longest-first / LPT). 2048 blocks -> 8 dispatched/CU, 5 LDS-resident,
// spares backfill as short blocks finish. bh fast-varying: same-bh blocks
// land on the same XCD (ids differ by 64). Round-9 lesson: keep 4-wave
// blocks + shared staging. Round-3 lesson: no min-waves bound.
// Round-12 lesson: 32 q-rows/wave regresses (VGPR 150+, occupancy drop).
__global__ __launch_bounds__(256) void k_attn(
    const __bf16* __restrict__ q, const __bf16* __restrict__ k,
    const __bf16* __restrict__ vt, __bf16* __restrict__ o) {
  __shared__ alignas(16) __bf16 Ks[2][64 * 64];
  __shared__ alignas(16) __bf16 Vs[2][64 * 64];
  const int t = threadIdx.x, w = t >> 6, l = t & 63;
  const int g = l >> 4, r16 = l & 15;
  const int bh = blockIdx.x;
  const int qt = 31 - blockIdx.y;
  const int qbase = qt * 64 + w * 16;
  const float sc = 0.125f * 1.44269504088896341f;  // 1/sqrt(64) * log2(e)

  auto scale8 = [&](bf16x8 v) {
    bf16x8 r;
#pragma unroll
    for (int j = 0; j < 8; ++j) r[j] = (__bf16)((float)v[j] * sc);
    return r;
  };
  const __bf16* qp = q + ((long)bh * T_ + qbase + r16) * HD_ + g * 8;
  const bf16x8 aq0 = scale8(*reinterpret_cast<const bf16x8*>(qp));
  const bf16x8 aq1 = scale8(*reinterpret_cast<const bf16x8*>(qp + 32));

  f32x4 oacc[4];
  float lrun = 0.f;
#pragma unroll
  for (int i = 0; i < 4; ++i) oacc[i] = (f32x4){0.f, 0.f, 0.f, 0.f};

  const int srow = t >> 3, sslot = t & 7;
  const int sswz = sslot ^ (srow & 7);
  const char* kg = (const char*)(k + ((long)bh * T_ + srow) * HD_) + sswz * 16;
  const char* vg = (const char*)(vt + ((long)bh * HD_ + srow) * T_) + sswz * 16;

  auto stage = [&](int buf, int kv0) {
    char* Kd = (char*)Ks[buf] + w * 1024;
    char* Vd = (char*)Vs[buf] + w * 1024;
    gload_lds16(kg + (long)kv0 * 128, Kd);
    gload_lds16(kg + (long)kv0 * 128 + 32 * 128, Kd + 4096);
    gload_lds16(vg + (long)kv0 * 2, Vd);
    gload_lds16(vg + (long)kv0 * 2 + 32 * (long)T_ * 2, Vd + 4096);
  };

  stage(0, 0);
  __syncthreads();

  const int ntile = qt + 1;
  for (int it = 0; it < ntile; ++it) {
    const int cur = it & 1;
    if (it + 1 < ntile) stage(cur ^ 1, (it + 1) * 64);
    const char* Kc = (const char*)Ks[cur];
    const char* Vc = (const char*)Vs[cur];

    f32x4 s[4];
    __builtin_amdgcn_s_setprio(1);
#pragma unroll
    for (int nf = 0; nf < 4; ++nf) {
      const char* kb = Kc + (nf * 16 + r16) * 128;
      const bf16x8 b0 = *reinterpret_cast<const bf16x8*>(kb + ((g ^ (r16 & 7)) << 4));
      const bf16x8 b1 = *reinterpret_cast<const bf16x8*>(kb + (((4 + g) ^ (r16 & 7)) << 4));
      f32x4 z = (f32x4){0.f, 0.f, 0.f, 0.f};
      z = __builtin_amdgcn_mfma_f32_16x16x32_bf16(b0, aq0, z, 0, 0, 0);
      z = __builtin_amdgcn_mfma_f32_16x16x32_bf16(b1, aq1, z, 0, 0, 0);
      s[nf] = z;
    }
    __builtin_amdgcn_s_setprio(0);

    bf16x8 pa0, pa1;
    soft_side(s, lrun, it == qt, qbase - it * 64, g, r16, pa0, pa1);

    __builtin_amdgcn_s_setprio(1);
#pragma unroll
    for (int nf = 0; nf < 4; ++nf) {
      const char* vb = Vc + (nf * 16 + r16) * 128;
      const bf16x8 v0 = *reinterpret_cast<const bf16x8*>(vb + ((g ^ (r16 & 7)) << 4));
      const bf16x8 v1 = *reinterpret_cast<const bf16x8*>(vb + (((4 + g) ^ (r16 & 7)) << 4));
      oacc[nf] = __builtin_amdgcn_mfma_f32_16x16x32_bf16(pa0, v0, oacc[nf], 0, 0, 0);
      oacc[nf] = __builtin_amdgcn_mfma_f32_16x16x32_bf16(pa1, v1, oacc[nf], 0, 0, 0);
    }
    __builtin_amdgcn_s_setprio(0);
    __syncthreads();
  }

  lrun += __shfl_xor(lrun, 16, 64);
  lrun += __shfl_xor(lrun, 32, 64);
  const float inv = 1.f / lrun;
  float invq[4];
#pragma unroll
  for (int rr = 0; rr < 4; ++rr) invq[rr] = __shfl(inv, 4 * g + rr, 64);
  const int b = bh >> 4, h = bh & 15;
#pragma unroll
  for (int nf = 0; nf < 4; ++nf) {
    const int hd = nf * 16 + r16;
#pragma unroll
    for (int rr = 0; rr < 4; ++rr) {
      const int tt = qbase + g * 4 + rr;
      o[((long)b * T_ + tt) * D_ + h * HD_ + hd] = (__bf16)(oacc[nf][rr] * invq[rr]);
    }
  }
}

// ---------------------------------------------------------------- launcher
extern "C" void kernel_launch(void* const* d_in, const int* in_sizes, int n_in,
                              void* d_out, int out_size, void* d_ws, size_t ws_size,
                              hipStream_t stream) {
  (void)in_sizes; (void)n_in; (void)out_size; (void)ws_size;
  const float* x     = (const float*)d_in[0];
  const float* Wqkv  = (const float*)d_in[1];
  const float* bqkv  = (const float*)d_in[2];
  const float* Wproj = (const float*)d_in[3];
  const float* bproj = (const float*)d_in[4];
  float* out = (float*)d_out;

  const long MT = (long)B_ * T_;          // 8192
  __bf16* xb     = (__bf16*)d_ws;                    // [8192][1024]
  __bf16* wqkvt  = xb + MT * D_;                     // [3072][1024]
  __bf16* wprojt = wqkvt + (long)3 * D_ * D_;        // [1024][1024]
  __bf16* qkvb   = wprojt + (long)D_ * D_;           // q,k: [2][B][H][T][64]
  __bf16* vtb    = qkvb + (long)2 * B_ * H_ * T_ * HD_;  // [B][H][64][T]
  __bf16* attno  = vtb + (long)B_ * H_ * HD_ * T_;   // [8192][1024]

  k_cvt_f32_bf16<<<2048, 256, 0, stream>>>(x, xb, (int)(MT * D_ / 4));
  k_transpose_bf16<float><<<dim3(48, 16, 1), 256, 0, stream>>>(Wqkv, wqkvt, D_, 3 * D_, 0, 0);
  k_transpose_bf16<float><<<dim3(16, 16, 1), 256, 0, stream>>>(Wproj, wprojt, D_, D_, 0, 0);
  k_gemm_bt<0><<<dim3(24, 64), 256, 0, stream>>>(xb, wqkvt, bqkv, qkvb, vtb, 8192, 3072, 1024);
  k_attn<<<dim3(64, 32), 256, 0, stream>>>(
      qkvb, qkvb + (long)B_ * H_ * T_ * HD_, vtb, attno);
  k_gemm_bt<1><<<dim3(8, 64), 256, 0, stream>>>(attno, wprojt, bproj, out, nullptr, 8192, 1024, 1024);
}

// Round 18
// 163.501 us; speedup vs baseline: 1.2392x; 1.0043x over previous
//
#include <hip/hip_runtime.h>

typedef float f32x4 __attribute__((ext_vector_type(4)));
typedef __bf16 bf16x8 __attribute__((ext_vector_type(8)));
typedef __bf16 bf16x4 __attribute__((ext_vector_type(4)));

#define B_ 4
#define T_ 2048
#define D_ 1024
#define H_ 16
#define HD_ 64

__device__ __forceinline__ void gload_lds16(const void* g, void* l) {
  __builtin_amdgcn_global_load_lds(
      (const __attribute__((address_space(1))) void*)g,
      (__attribute__((address_space(3))) void*)l, 16, 0, 0);
}

// ---------------------------------------------------------------- convert x
__global__ __launch_bounds__(256) void k_cvt_f32_bf16(
    const float* __restrict__ in, __bf16* __restrict__ out, int n4) {
  int i = blockIdx.x * blockDim.x + threadIdx.x;
  int stride = gridDim.x * blockDim.x;
  for (; i < n4; i += stride) {
    float4 v = reinterpret_cast<const float4*>(in)[i];
    bf16x4 o = { (__bf16)v.x, (__bf16)v.y, (__bf16)v.z, (__bf16)v.w };
    reinterpret_cast<bf16x4*>(out)[i] = o;
  }
}

// ------------------------------------------- transpose (+convert) to bf16
template <typename Tin>
__global__ __launch_bounds__(256) void k_transpose_bf16(
    const Tin* __restrict__ in, __bf16* __restrict__ out,
    int R, int C, long inb, long outb) {
  __shared__ alignas(16) __bf16 lds[64 * 68];
  const int t = threadIdx.x;
  in  += (long)blockIdx.z * inb;
  out += (long)blockIdx.z * outb;
  const int r0 = blockIdx.y * 64, c0 = blockIdx.x * 64;
#pragma unroll
  for (int i = 0; i < 16; ++i) {
    int e = i * 256 + t, row = e >> 6, col = e & 63;
    lds[row * 68 + col] = (__bf16)(float)in[(long)(r0 + row) * C + c0 + col];
  }
  __syncthreads();
#pragma unroll
  for (int i = 0; i < 16; ++i) {
    int e = i * 256 + t, orow = e >> 6, ocol = e & 63;
    out[(long)(c0 + orow) * R + r0 + ocol] = lds[ocol * 68 + orow];
  }
}

// -------------------------------------------------------- QKV GEMM (256x128)
// BM=256, BN=128, BK=32, 512 thr (8 waves 4Mx2N, 64x64 per wave), 48KB
// dbuf LDS (3 blocks/CU resident, 24 waves/CU), 2-phase overlap, XOR
// swizzle (pre-swizzled global source + XOR'd read slot) -- the verified
// round-6..17 structure with a taller A-panel: staging bytes per FLOP
// drop 0.75x (3 loads/thread/iter vs 4), grid (24,32)=768 = exactly
// 3.0 blocks/CU. Inner loop/epilogue byte-identical index algebra.
__global__ __launch_bounds__(512) void k_gemm_qkv256(
    const __bf16* __restrict__ A, const __bf16* __restrict__ Bt,
    const float* __restrict__ bias, __bf16* __restrict__ qkvb,
    __bf16* __restrict__ vout) {
  __shared__ alignas(16) __bf16 As[2][256 * 32];   // 2 x 16KB
  __shared__ alignas(16) __bf16 Bs[2][128 * 32];   // 2 x 8KB
  const int t = threadIdx.x;                 // 0..511
  const int w = t >> 6, l = t & 63;
  const int g = l >> 4, r16 = l & 15;
  const int wm = w >> 1, wn = w & 1;         // 4 x 2 wave grid
  const int m0 = blockIdx.y * 256, n0 = blockIdx.x * 128;
  const int K = 1024;

  f32x4 acc[4][4];
#pragma unroll
  for (int i = 0; i < 4; ++i)
#pragma unroll
    for (int j = 0; j < 4; ++j) acc[i][j] = (f32x4){0.f, 0.f, 0.f, 0.f};

  const int arow = t >> 2;                                  // 0..127
  const int acol = ((t & 3) ^ ((t >> 3) & 3)) * 8;          // pre-swizzled src
  const char* Ag = (const char*)(A + (long)(m0 + arow) * K + acol);
  const char* Bg = (const char*)(Bt + (long)(n0 + arow) * K + acol);
  const long rowskipA = (long)128 * K * 2;   // second A half (rows 128..255)
  const int rdsw = (g ^ ((r16 >> 1) & 3)) * 8;              // read-side slot

  auto stage = [&](int buf, long koff) {
    char* AsW = (char*)As[buf] + w * 1024;
    char* BsW = (char*)Bs[buf] + w * 1024;
    gload_lds16(Ag + koff, AsW);
    gload_lds16(Ag + koff + rowskipA, AsW + 8192);
    gload_lds16(Bg + koff, BsW);
  };

  stage(0, 0);
  __syncthreads();

  for (int kt = 0; kt < K; kt += 32) {
    const int cur = (kt >> 5) & 1;
    if (kt + 32 < K) stage(cur ^ 1, (long)(kt + 32) * 2);
    bf16x8 af[4], bfr[4];
#pragma unroll
    for (int mi = 0; mi < 4; ++mi)
      af[mi] = *reinterpret_cast<const bf16x8*>(
          &As[cur][(wm * 64 + mi * 16 + r16) * 32 + rdsw]);
#pragma unroll
    for (int ni = 0; ni < 4; ++ni)
      bfr[ni] = *reinterpret_cast<const bf16x8*>(
          &Bs[cur][(wn * 64 + ni * 16 + r16) * 32 + rdsw]);
    __builtin_amdgcn_s_setprio(1);
#pragma unroll
    for (int mi = 0; mi < 4; ++mi)
#pragma unroll
      for (int ni = 0; ni < 4; ++ni)
        acc[mi][ni] = __builtin_amdgcn_mfma_f32_16x16x32_bf16(af[mi], bfr[ni], acc[mi][ni], 0, 0, 0);
    __builtin_amdgcn_s_setprio(0);
    __syncthreads();
  }

  const int which = n0 >> 10;            // block-uniform (128 | 1024)
#pragma unroll
  for (int mi = 0; mi < 4; ++mi) {
#pragma unroll
    for (int ni = 0; ni < 4; ++ni) {
      const int n = n0 + wn * 64 + ni * 16 + r16;
      const float bv = bias[n];
      f32x4 c = acc[mi][ni];
      const int rem = n & 1023, h = rem >> 6, hd = rem & 63;
      const int mbase = m0 + wm * 64 + mi * 16 + g * 4;
      const int b = mbase >> 11, tt0 = mbase & 2047;
      if (which < 2) {
#pragma unroll
        for (int r = 0; r < 4; ++r)
          qkvb[((long)((which * B_ + b) * H_ + h) * T_ + tt0 + r) * HD_ + hd] =
              (__bf16)(c[r] + bv);
      } else {
        bf16x4 pk = { (__bf16)(c[0] + bv), (__bf16)(c[1] + bv),
                      (__bf16)(c[2] + bv), (__bf16)(c[3] + bv) };
        *reinterpret_cast<bf16x4*>(
            &vout[(((long)b * H_ + h) * HD_ + hd) * T_ + tt0]) = pk;
      }
    }
  }
}

// ---------------------------------------------------------------- GEMM (bt)
// 128x128 tile, BK=32, 2-phase dbuf, XOR-swizzled LDS (proj: f32 out).
// Round-16 lesson: no operand-swapped MFMA (perturbs main-loop codegen).
__global__ __launch_bounds__(256) void k_gemm_proj(
    const __bf16* __restrict__ A, const __bf16* __restrict__ Bt,
    const float* __restrict__ bias, float* __restrict__ O,
    int M, int N, int K) {
  __shared__ alignas(16) __bf16 As[2][128 * 32];
  __shared__ alignas(16) __bf16 Bs[2][128 * 32];
  const int t = threadIdx.x;
  const int w = t >> 6, l = t & 63;
  const int g = l >> 4, r16 = l & 15;
  const int wr = w >> 1, wc = w & 1;
  const int m0 = blockIdx.y * 128, n0 = blockIdx.x * 128;

  f32x4 acc[4][4];
#pragma unroll
  for (int i = 0; i < 4; ++i)
#pragma unroll
    for (int j = 0; j < 4; ++j) acc[i][j] = (f32x4){0.f, 0.f, 0.f, 0.f};

  const int arow = t >> 2;
  const int acol = ((t & 3) ^ ((t >> 3) & 3)) * 8;
  const char* Ag = (const char*)(A + (long)(m0 + arow) * K + acol);
  const char* Bg = (const char*)(Bt + (long)(n0 + arow) * K + acol);
  const long rowskip = (long)64 * K * 2;
  const int rdsw = (g ^ ((r16 >> 1) & 3)) * 8;

  auto stage = [&](int buf, long koff) {
    char* AsW = (char*)As[buf] + w * 1024;
    char* BsW = (char*)Bs[buf] + w * 1024;
    gload_lds16(Ag + koff, AsW);
    gload_lds16(Ag + koff + rowskip, AsW + 4096);
    gload_lds16(Bg + koff, BsW);
    gload_lds16(Bg + koff + rowskip, BsW + 4096);
  };

  stage(0, 0);
  __syncthreads();

  for (int kt = 0; kt < K; kt += 32) {
    const int cur = (kt >> 5) & 1;
    if (kt + 32 < K) stage(cur ^ 1, (long)(kt + 32) * 2);
    bf16x8 af[4], bfr[4];
#pragma unroll
    for (int mi = 0; mi < 4; ++mi)
      af[mi] = *reinterpret_cast<const bf16x8*>(
          &As[cur][(wr * 64 + mi * 16 + r16) * 32 + rdsw]);
#pragma unroll
    for (int ni = 0; ni < 4; ++ni)
      bfr[ni] = *reinterpret_cast<const bf16x8*>(
          &Bs[cur][(wc * 64 + ni * 16 + r16) * 32 + rdsw]);
    __builtin_amdgcn_s_setprio(1);
#pragma unroll
    for (int mi = 0; mi < 4; ++mi)
#pragma unroll
      for (int ni = 0; ni < 4; ++ni)
        acc[mi][ni] = __builtin_amdgcn_mfma_f32_16x16x32_bf16(af[mi], bfr[ni], acc[mi][ni], 0, 0, 0);
    __builtin_amdgcn_s_setprio(0);
    __syncthreads();
  }

#pragma unroll
  for (int mi = 0; mi < 4; ++mi) {
#pragma unroll
    for (int ni = 0; ni < 4; ++ni) {
      const int n = n0 + wc * 64 + ni * 16 + r16;
      const float bv = bias[n];
      f32x4 c = acc[mi][ni];
      const int mbase = m0 + wr * 64 + mi * 16 + g * 4;
#pragma unroll
      for (int r = 0; r < 4; ++r) O[(long)(mbase + r) * N + n] = c[r] + bv;
    }
  }
}

// ---------------------------------------------------------------- attention
// Swapped-QK^T softmax, Q pre-scaled (log2-domain), no max tracking,
// raw v_exp_f32, in-register P via cvt_pk + permlane32/16 swaps.
__device__ __forceinline__ void soft_side(
    const f32x4 (&s)[4], float& lrun, bool diag, int qrel,
    int g, int r16, bf16x8& pa0, bf16x8& pa1) {
  float p[4][4];
#pragma unroll
  for (int nf = 0; nf < 4; ++nf) {
#pragma unroll
    for (int rr = 0; rr < 4; ++rr) {
      float x = s[nf][rr];
      if (diag) x = (nf * 16 + 4 * g + rr <= qrel + r16) ? x : -1e30f;
      p[nf][rr] = __builtin_amdgcn_exp2f(x);  // 2^-1e30 -> +0
    }
  }
  const float ps0 = (p[0][0] + p[0][1]) + (p[0][2] + p[0][3]);
  const float ps1 = (p[1][0] + p[1][1]) + (p[1][2] + p[1][3]);
  const float ps2 = (p[2][0] + p[2][1]) + (p[2][2] + p[2][3]);
  const float ps3 = (p[3][0] + p[3][1]) + (p[3][2] + p[3][3]);
  lrun += (ps0 + ps1) + (ps2 + ps3);

  unsigned u[4][2];
#pragma unroll
  for (int nf = 0; nf < 4; ++nf) {
    asm("v_cvt_pk_bf16_f32 %0, %1, %2"
        : "=v"(u[nf][0]) : "v"(p[nf][0]), "v"(p[nf][1]));
    asm("v_cvt_pk_bf16_f32 %0, %1, %2"
        : "=v"(u[nf][1]) : "v"(p[nf][2]), "v"(p[nf][3]));
  }
#pragma unroll
  for (int j = 0; j < 2; ++j) {
    asm("v_permlane32_swap_b32 %0, %1" : "+v"(u[0][j]), "+v"(u[1][j]));
    asm("v_permlane32_swap_b32 %0, %1" : "+v"(u[2][j]), "+v"(u[3][j]));
  }
#pragma unroll
  for (int j = 0; j < 2; ++j) {
    asm("v_permlane16_swap_b32 %0, %1" : "+v"(u[0][j]), "+v"(u[1][j]));
    asm("v_permlane16_swap_b32 %0, %1" : "+v"(u[2][j]), "+v"(u[3][j]));
  }
  union PU { unsigned w[4]; bf16x8 v; };
  PU a0, a1;
  a0.w[0] = u[0][0]; a0.w[1] = u[0][1]; a0.w[2] = u[1][0]; a0.w[3] = u[1][1];
  a1.w[0] = u[2][0]; a1.w[1] = u[2][1]; a1.w[2] = u[3][0]; a1.w[3] = u[3][1];
  pa0 = a0.v;
  pa1 = a1.v;
}

// UNPAIRED: one block = one 64-row q-tile. grid (bh=64, y=32), qt=31-y
// (LPT). 2048 blocks -> backfill; bh fast-varying -> same-bh on one XCD.
__global__ __launch_bounds__(256) void k_attn(
    const __bf16* __restrict__ q, const __bf16* __restrict__ k,
    const __bf16* __restrict__ vt, __bf16* __restrict__ o) {
  __shared__ alignas(16) __bf16 Ks[2][64 * 64];
  __shared__ alignas(16) __bf16 Vs[2][64 * 64];
  const int t = threadIdx.x, w = t >> 6, l = t & 63;
  const int g = l >> 4, r16 = l & 15;
  const int bh = blockIdx.x;
  const int qt = 31 - blockIdx.y;
  const int qbase = qt * 64 + w * 16;
  const float sc = 0.125f * 1.44269504088896341f;  // 1/sqrt(64) * log2(e)

  auto scale8 = [&](bf16x8 v) {
    bf16x8 r;
#pragma unroll
    for (int j = 0; j < 8; ++j) r[j] = (__bf16)((float)v[j] * sc);
    return r;
  };
  const __bf16* qp = q + ((long)bh * T_ + qbase + r16) * HD_ + g * 8;
  const bf16x8 aq0 = scale8(*reinterpret_cast<const bf16x8*>(qp));
  const bf16x8 aq1 = scale8(*reinterpret_cast<const bf16x8*>(qp + 32));

  f32x4 oacc[4];
  float lrun = 0.f;
#pragma unroll
  for (int i = 0; i < 4; ++i) oacc[i] = (f32x4){0.f, 0.f, 0.f, 0.f};

  const int srow = t >> 3, sslot = t & 7;
  const int sswz = sslot ^ (srow & 7);
  const char* kg = (const char*)(k + ((long)bh * T_ + srow) * HD_) + sswz * 16;
  const char* vg = (const char*)(vt + ((long)bh * HD_ + srow) * T_) + sswz * 16;

  auto stage = [&](int buf, int kv0) {
    char* Kd = (char*)Ks[buf] + w * 1024;
    char* Vd = (char*)Vs[buf] + w * 1024;
    gload_lds16(kg + (long)kv0 * 128, Kd);
    gload_lds16(kg + (long)kv0 * 128 + 32 * 128, Kd + 4096);
    gload_lds16(vg + (long)kv0 * 2, Vd);
    gload_lds16(vg + (long)kv0 * 2 + 32 * (long)T_ * 2, Vd + 4096);
  };

  stage(0, 0);
  __syncthreads();

  const int ntile = qt + 1;
  for (int it = 0; it < ntile; ++it) {
    const int cur = it & 1;
    if (it + 1 < ntile) stage(cur ^ 1, (it + 1) * 64);
    const char* Kc = (const char*)Ks[cur];
    const char* Vc = (const char*)Vs[cur];

    f32x4 s[4];
    __builtin_amdgcn_s_setprio(1);
#pragma unroll
    for (int nf = 0; nf < 4; ++nf) {
      const char* kb = Kc + (nf * 16 + r16) * 128;
      const bf16x8 b0 = *reinterpret_cast<const bf16x8*>(kb + ((g ^ (r16 & 7)) << 4));
      const bf16x8 b1 = *reinterpret_cast<const bf16x8*>(kb + (((4 + g) ^ (r16 & 7)) << 4));
      f32x4 z = (f32x4){0.f, 0.f, 0.f, 0.f};
      z = __builtin_amdgcn_mfma_f32_16x16x32_bf16(b0, aq0, z, 0, 0, 0);
      z = __builtin_amdgcn_mfma_f32_16x16x32_bf16(b1, aq1, z, 0, 0, 0);
      s[nf] = z;
    }
    __builtin_amdgcn_s_setprio(0);

    bf16x8 pa0, pa1;
    soft_side(s, lrun, it == qt, qbase - it * 64, g, r16, pa0, pa1);

    __builtin_amdgcn_s_setprio(1);
#pragma unroll
    for (int nf = 0; nf < 4; ++nf) {
      const char* vb = Vc + (nf * 16 + r16) * 128;
      const bf16x8 v0 = *reinterpret_cast<const bf16x8*>(vb + ((g ^ (r16 & 7)) << 4));
      const bf16x8 v1 = *reinterpret_cast<const bf16x8*>(vb + (((4 + g) ^ (r16 & 7)) << 4));
      oacc[nf] = __builtin_amdgcn_mfma_f32_16x16x32_bf16(pa0, v0, oacc[nf], 0, 0, 0);
      oacc[nf] = __builtin_amdgcn_mfma_f32_16x16x32_bf16(pa1, v1, oacc[nf], 0, 0, 0);
    }
    __builtin_amdgcn_s_setprio(0);
    __syncthreads();
  }

  lrun += __shfl_xor(lrun, 16, 64);
  lrun += __shfl_xor(lrun, 32, 64);
  const float inv = 1.f / lrun;
  float invq[4];
#pragma unroll
  for (int rr = 0; rr < 4; ++rr) invq[rr] = __shfl(inv, 4 * g + rr, 64);
  const int b = bh >> 4, h = bh & 15;
#pragma unroll
  for (int nf = 0; nf < 4; ++nf) {
    const int hd = nf * 16 + r16;
#pragma unroll
    for (int rr = 0; rr < 4; ++rr) {
      const int tt = qbase + g * 4 + rr;
      o[((long)b * T_ + tt) * D_ + h * HD_ + hd] = (__bf16)(oacc[nf][rr] * invq[rr]);
    }
  }
}

// ---------------------------------------------------------------- launcher
extern "C" void kernel_launch(void* const* d_in, const int* in_sizes, int n_in,
                              void* d_out, int out_size, void* d_ws, size_t ws_size,
                              hipStream_t stream) {
  (void)in_sizes; (void)n_in; (void)out_size; (void)ws_size;
  const float* x     = (const float*)d_in[0];
  const float* Wqkv  = (const float*)d_in[1];
  const float* bqkv  = (const float*)d_in[2];
  const float* Wproj = (const float*)d_in[3];
  const float* bproj = (const float*)d_in[4];
  float* out = (float*)d_out;

  const long MT = (long)B_ * T_;          // 8192
  __bf16* xb     = (__bf16*)d_ws;                    // [8192][1024]
  __bf16* wqkvt  = xb + MT * D_;                     // [3072][1024]
  __bf16* wprojt = wqkvt + (long)3 * D_ * D_;        // [1024][1024]
  __bf16* qkvb   = wprojt + (long)D_ * D_;           // q,k: [2][B][H][T][64]
  __bf16* vtb    = qkvb + (long)2 * B_ * H_ * T_ * HD_;  // [B][H][64][T]
  __bf16* attno  = vtb + (long)B_ * H_ * HD_ * T_;   // [8192][1024]

  k_cvt_f32_bf16<<<2048, 256, 0, stream>>>(x, xb, (int)(MT * D_ / 4));
  k_transpose_bf16<float><<<dim3(48, 16, 1), 256, 0, stream>>>(Wqkv, wqkvt, D_, 3 * D_, 0, 0);
  k_transpose_bf16<float><<<dim3(16, 16, 1), 256, 0, stream>>>(Wproj, wprojt, D_, D_, 0, 0);
  k_gemm_qkv256<<<dim3(24, 32), 512, 0, stream>>>(xb, wqkvt, bqkv, qkvb, vtb);
  k_attn<<<dim3(64, 32), 256, 0, stream>>>(
      qkvb, qkvb + (long)B_ * H_ * T_ * HD_, vtb, attno);
  k_gemm_proj<<<dim3(8, 64), 256, 0, stream>>>(attno, wprojt, bproj, out, 8192, 1024, 1024);
}

// Round 19
// 159.947 us; speedup vs baseline: 1.2668x; 1.0222x over previous
//
#include <hip/hip_runtime.h>

typedef float f32x4 __attribute__((ext_vector_type(4)));
typedef __bf16 bf16x8 __attribute__((ext_vector_type(8)));
typedef __bf16 bf16x4 __attribute__((ext_vector_type(4)));

#define B_ 4
#define T_ 2048
#define D_ 1024
#define H_ 16
#define HD_ 64

__device__ __forceinline__ void gload_lds16(const void* g, void* l) {
  __builtin_amdgcn_global_load_lds(
      (const __attribute__((address_space(1))) void*)g,
      (__attribute__((address_space(3))) void*)l, 16, 0, 0);
}

// ---------------------------------------------------------------- convert x
__global__ __launch_bounds__(256) void k_cvt_f32_bf16(
    const float* __restrict__ in, __bf16* __restrict__ out, int n4) {
  int i = blockIdx.x * blockDim.x + threadIdx.x;
  int stride = gridDim.x * blockDim.x;
  for (; i < n4; i += stride) {
    float4 v = reinterpret_cast<const float4*>(in)[i];
    bf16x4 o = { (__bf16)v.x, (__bf16)v.y, (__bf16)v.z, (__bf16)v.w };
    reinterpret_cast<bf16x4*>(out)[i] = o;
  }
}

// ------------------------------------------- transpose (+convert) to bf16
template <typename Tin>
__global__ __launch_bounds__(256) void k_transpose_bf16(
    const Tin* __restrict__ in, __bf16* __restrict__ out,
    int R, int C, long inb, long outb) {
  __shared__ alignas(16) __bf16 lds[64 * 68];
  const int t = threadIdx.x;
  in  += (long)blockIdx.z * inb;
  out += (long)blockIdx.z * outb;
  const int r0 = blockIdx.y * 64, c0 = blockIdx.x * 64;
#pragma unroll
  for (int i = 0; i < 16; ++i) {
    int e = i * 256 + t, row = e >> 6, col = e & 63;
    lds[row * 68 + col] = (__bf16)(float)in[(long)(r0 + row) * C + c0 + col];
  }
  __syncthreads();
#pragma unroll
  for (int i = 0; i < 16; ++i) {
    int e = i * 256 + t, orow = e >> 6, ocol = e & 63;
    out[(long)(c0 + orow) * R + r0 + ocol] = lds[ocol * 68 + orow];
  }
}

// -------------------------------------------------------- QKV GEMM (256x128)
// BM=256, BN=128, BK=32, 512 thr, 48KB dbuf LDS, 2-phase, XOR swizzle.
// NEW (round 19): T1 XCD-aware chunked block swizzle. Linear dispatch
// round-robins consecutive ids across 8 XCDs, so the 24 blocks sharing
// one A-panel hit 8 different L2s (FETCH 71.8MB vs 22MB unique = 3.3x
// over-fetch). swz = (lin&7)*96 + lin>>3 gives each XCD 4 contiguous
// M-panels (all N-blocks) -> A-panels single-XCD L2-resident.
__global__ __launch_bounds__(512) void k_gemm_qkv256(
    const __bf16* __restrict__ A, const __bf16* __restrict__ Bt,
    const float* __restrict__ bias, __bf16* __restrict__ qkvb,
    __bf16* __restrict__ vout) {
  __shared__ alignas(16) __bf16 As[2][256 * 32];   // 2 x 16KB
  __shared__ alignas(16) __bf16 Bs[2][128 * 32];   // 2 x 8KB
  const int t = threadIdx.x;                 // 0..511
  const int w = t >> 6, l = t & 63;
  const int g = l >> 4, r16 = l & 15;
  const int wm = w >> 1, wn = w & 1;         // 4 x 2 wave grid
  // T1 chunked XCD swizzle: grid (24,32), nwg=768, cpx=96.
  const int lin = blockIdx.y * 24 + blockIdx.x;
  const int swz = (lin & 7) * 96 + (lin >> 3);
  const int bx = swz % 24, by = swz / 24;
  const int m0 = by * 256, n0 = bx * 128;
  const int K = 1024;

  f32x4 acc[4][4];
#pragma unroll
  for (int i = 0; i < 4; ++i)
#pragma unroll
    for (int j = 0; j < 4; ++j) acc[i][j] = (f32x4){0.f, 0.f, 0.f, 0.f};

  const int arow = t >> 2;                                  // 0..127
  const int acol = ((t & 3) ^ ((t >> 3) & 3)) * 8;          // pre-swizzled src
  const char* Ag = (const char*)(A + (long)(m0 + arow) * K + acol);
  const char* Bg = (const char*)(Bt + (long)(n0 + arow) * K + acol);
  const long rowskipA = (long)128 * K * 2;   // second A half (rows 128..255)
  const int rdsw = (g ^ ((r16 >> 1) & 3)) * 8;              // read-side slot

  auto stage = [&](int buf, long koff) {
    char* AsW = (char*)As[buf] + w * 1024;
    char* BsW = (char*)Bs[buf] + w * 1024;
    gload_lds16(Ag + koff, AsW);
    gload_lds16(Ag + koff + rowskipA, AsW + 8192);
    gload_lds16(Bg + koff, BsW);
  };

  stage(0, 0);
  __syncthreads();

  for (int kt = 0; kt < K; kt += 32) {
    const int cur = (kt >> 5) & 1;
    if (kt + 32 < K) stage(cur ^ 1, (long)(kt + 32) * 2);
    bf16x8 af[4], bfr[4];
#pragma unroll
    for (int mi = 0; mi < 4; ++mi)
      af[mi] = *reinterpret_cast<const bf16x8*>(
          &As[cur][(wm * 64 + mi * 16 + r16) * 32 + rdsw]);
#pragma unroll
    for (int ni = 0; ni < 4; ++ni)
      bfr[ni] = *reinterpret_cast<const bf16x8*>(
          &Bs[cur][(wn * 64 + ni * 16 + r16) * 32 + rdsw]);
    __builtin_amdgcn_s_setprio(1);
#pragma unroll
    for (int mi = 0; mi < 4; ++mi)
#pragma unroll
      for (int ni = 0; ni < 4; ++ni)
        acc[mi][ni] = __builtin_amdgcn_mfma_f32_16x16x32_bf16(af[mi], bfr[ni], acc[mi][ni], 0, 0, 0);
    __builtin_amdgcn_s_setprio(0);
    __syncthreads();
  }

  const int which = n0 >> 10;            // block-uniform (128 | 1024)
#pragma unroll
  for (int mi = 0; mi < 4; ++mi) {
#pragma unroll
    for (int ni = 0; ni < 4; ++ni) {
      const int n = n0 + wn * 64 + ni * 16 + r16;
      const float bv = bias[n];
      f32x4 c = acc[mi][ni];
      const int rem = n & 1023, h = rem >> 6, hd = rem & 63;
      const int mbase = m0 + wm * 64 + mi * 16 + g * 4;
      const int b = mbase >> 11, tt0 = mbase & 2047;
      if (which < 2) {
#pragma unroll
        for (int r = 0; r < 4; ++r)
          qkvb[((long)((which * B_ + b) * H_ + h) * T_ + tt0 + r) * HD_ + hd] =
              (__bf16)(c[r] + bv);
      } else {
        bf16x4 pk = { (__bf16)(c[0] + bv), (__bf16)(c[1] + bv),
                      (__bf16)(c[2] + bv), (__bf16)(c[3] + bv) };
        *reinterpret_cast<bf16x4*>(
            &vout[(((long)b * H_ + h) * HD_ + hd) * T_ + tt0]) = pk;
      }
    }
  }
}

// ---------------------------------------------------------------- GEMM (bt)
// 128x128 tile, BK=32, 2-phase dbuf, XOR-swizzled LDS (proj: f32 out).
// T1 chunked XCD swizzle (grid (8,64), nwg=512, cpx=64).
__global__ __launch_bounds__(256) void k_gemm_proj(
    const __bf16* __restrict__ A, const __bf16* __restrict__ Bt,
    const float* __restrict__ bias, float* __restrict__ O,
    int M, int N, int K) {
  __shared__ alignas(16) __bf16 As[2][128 * 32];
  __shared__ alignas(16) __bf16 Bs[2][128 * 32];
  const int t = threadIdx.x;
  const int w = t >> 6, l = t & 63;
  const int g = l >> 4, r16 = l & 15;
  const int wr = w >> 1, wc = w & 1;
  const int lin = blockIdx.y * 8 + blockIdx.x;
  const int swz = (lin & 7) * 64 + (lin >> 3);
  const int bx = swz & 7, by = swz >> 3;
  const int m0 = by * 128, n0 = bx * 128;

  f32x4 acc[4][4];
#pragma unroll
  for (int i = 0; i < 4; ++i)
#pragma unroll
    for (int j = 0; j < 4; ++j) acc[i][j] = (f32x4){0.f, 0.f, 0.f, 0.f};

  const int arow = t >> 2;
  const int acol = ((t & 3) ^ ((t >> 3) & 3)) * 8;
  const char* Ag = (const char*)(A + (long)(m0 + arow) * K + acol);
  const char* Bg = (const char*)(Bt + (long)(n0 + arow) * K + acol);
  const long rowskip = (long)64 * K * 2;
  const int rdsw = (g ^ ((r16 >> 1) & 3)) * 8;

  auto stage = [&](int buf, long koff) {
    char* AsW = (char*)As[buf] + w * 1024;
    char* BsW = (char*)Bs[buf] + w * 1024;
    gload_lds16(Ag + koff, AsW);
    gload_lds16(Ag + koff + rowskip, AsW + 4096);
    gload_lds16(Bg + koff, BsW);
    gload_lds16(Bg + koff + rowskip, BsW + 4096);
  };

  stage(0, 0);
  __syncthreads();

  for (int kt = 0; kt < K; kt += 32) {
    const int cur = (kt >> 5) & 1;
    if (kt + 32 < K) stage(cur ^ 1, (long)(kt + 32) * 2);
    bf16x8 af[4], bfr[4];
#pragma unroll
    for (int mi = 0; mi < 4; ++mi)
      af[mi] = *reinterpret_cast<const bf16x8*>(
          &As[cur][(wr * 64 + mi * 16 + r16) * 32 + rdsw]);
#pragma unroll
    for (int ni = 0; ni < 4; ++ni)
      bfr[ni] = *reinterpret_cast<const bf16x8*>(
          &Bs[cur][(wc * 64 + ni * 16 + r16) * 32 + rdsw]);
    __builtin_amdgcn_s_setprio(1);
#pragma unroll
    for (int mi = 0; mi < 4; ++mi)
#pragma unroll
      for (int ni = 0; ni < 4; ++ni)
        acc[mi][ni] = __builtin_amdgcn_mfma_f32_16x16x32_bf16(af[mi], bfr[ni], acc[mi][ni], 0, 0, 0);
    __builtin_amdgcn_s_setprio(0);
    __syncthreads();
  }

#pragma unroll
  for (int mi = 0; mi < 4; ++mi) {
#pragma unroll
    for (int ni = 0; ni < 4; ++ni) {
      const int n = n0 + wc * 64 + ni * 16 + r16;
      const float bv = bias[n];
      f32x4 c = acc[mi][ni];
      const int mbase = m0 + wr * 64 + mi * 16 + g * 4;
#pragma unroll
      for (int r = 0; r < 4; ++r) O[(long)(mbase + r) * N + n] = c[r] + bv;
    }
  }
}

// ---------------------------------------------------------------- attention
// Swapped-QK^T softmax, Q pre-scaled (log2-domain), no max tracking,
// raw v_exp_f32, in-register P via cvt_pk + permlane32/16 swaps.
__device__ __forceinline__ void soft_side(
    const f32x4 (&s)[4], float& lrun, bool diag, int qrel,
    int g, int r16, bf16x8& pa0, bf16x8& pa1) {
  float p[4][4];
#pragma unroll
  for (int nf = 0; nf < 4; ++nf) {
#pragma unroll
    for (int rr = 0; rr < 4; ++rr) {
      float x = s[nf][rr];
      if (diag) x = (nf * 16 + 4 * g + rr <= qrel + r16) ? x : -1e30f;
      p[nf][rr] = __builtin_amdgcn_exp2f(x);  // 2^-1e30 -> +0
    }
  }
  const float ps0 = (p[0][0] + p[0][1]) + (p[0][2] + p[0][3]);
  const float ps1 = (p[1][0] + p[1][1]) + (p[1][2] + p[1][3]);
  const float ps2 = (p[2][0] + p[2][1]) + (p[2][2] + p[2][3]);
  const float ps3 = (p[3][0] + p[3][1]) + (p[3][2] + p[3][3]);
  lrun += (ps0 + ps1) + (ps2 + ps3);

  unsigned u[4][2];
#pragma unroll
  for (int nf = 0; nf < 4; ++nf) {
    asm("v_cvt_pk_bf16_f32 %0, %1, %2"
        : "=v"(u[nf][0]) : "v"(p[nf][0]), "v"(p[nf][1]));
    asm("v_cvt_pk_bf16_f32 %0, %1, %2"
        : "=v"(u[nf][1]) : "v"(p[nf][2]), "v"(p[nf][3]));
  }
#pragma unroll
  for (int j = 0; j < 2; ++j) {
    asm("v_permlane32_swap_b32 %0, %1" : "+v"(u[0][j]), "+v"(u[1][j]));
    asm("v_permlane32_swap_b32 %0, %1" : "+v"(u[2][j]), "+v"(u[3][j]));
  }
#pragma unroll
  for (int j = 0; j < 2; ++j) {
    asm("v_permlane16_swap_b32 %0, %1" : "+v"(u[0][j]), "+v"(u[1][j]));
    asm("v_permlane16_swap_b32 %0, %1" : "+v"(u[2][j]), "+v"(u[3][j]));
  }
  union PU { unsigned w[4]; bf16x8 v; };
  PU a0, a1;
  a0.w[0] = u[0][0]; a0.w[1] = u[0][1]; a0.w[2] = u[1][0]; a0.w[3] = u[1][1];
  a1.w[0] = u[2][0]; a1.w[1] = u[2][1]; a1.w[2] = u[3][0]; a1.w[3] = u[3][1];
  pa0 = a0.v;
  pa1 = a1.v;
}

// UNPAIRED: one block = one 64-row q-tile. grid (bh=64, y=32), qt=31-y
// (LPT). 2048 blocks -> backfill; bh fast-varying -> same-bh on one XCD.
__global__ __launch_bounds__(256) void k_attn(
    const __bf16* __restrict__ q, const __bf16* __restrict__ k,
    const __bf16* __restrict__ vt, __bf16* __restrict__ o) {
  __shared__ alignas(16) __bf16 Ks[2][64 * 64];
  __shared__ alignas(16) __bf16 Vs[2][64 * 64];
  const int t = threadIdx.x, w = t >> 6, l = t & 63;
  const int g = l >> 4, r16 = l & 15;
  const int bh = blockIdx.x;
  const int qt = 31 - blockIdx.y;
  const int qbase = qt * 64 + w * 16;
  const float sc = 0.125f * 1.44269504088896341f;  // 1/sqrt(64) * log2(e)

  auto scale8 = [&](bf16x8 v) {
    bf16x8 r;
#pragma unroll
    for (int j = 0; j < 8; ++j) r[j] = (__bf16)((float)v[j] * sc);
    return r;
  };
  const __bf16* qp = q + ((long)bh * T_ + qbase + r16) * HD_ + g * 8;
  const bf16x8 aq0 = scale8(*reinterpret_cast<const bf16x8*>(qp));
  const bf16x8 aq1 = scale8(*reinterpret_cast<const bf16x8*>(qp + 32));

  f32x4 oacc[4];
  float lrun = 0.f;
#pragma unroll
  for (int i = 0; i < 4; ++i) oacc[i] = (f32x4){0.f, 0.f, 0.f, 0.f};

  const int srow = t >> 3, sslot = t & 7;
  const int sswz = sslot ^ (srow & 7);
  const char* kg = (const char*)(k + ((long)bh * T_ + srow) * HD_) + sswz * 16;
  const char* vg = (const char*)(vt + ((long)bh * HD_ + srow) * T_) + sswz * 16;

  auto stage = [&](int buf, int kv0) {
    char* Kd = (char*)Ks[buf] + w * 1024;
    char* Vd = (char*)Vs[buf] + w * 1024;
    gload_lds16(kg + (long)kv0 * 128, Kd);
    gload_lds16(kg + (long)kv0 * 128 + 32 * 128, Kd + 4096);
    gload_lds16(vg + (long)kv0 * 2, Vd);
    gload_lds16(vg + (long)kv0 * 2 + 32 * (long)T_ * 2, Vd + 4096);
  };

  stage(0, 0);
  __syncthreads();

  const int ntile = qt + 1;
  for (int it = 0; it < ntile; ++it) {
    const int cur = it & 1;
    if (it + 1 < ntile) stage(cur ^ 1, (it + 1) * 64);
    const char* Kc = (const char*)Ks[cur];
    const char* Vc = (const char*)Vs[cur];

    f32x4 s[4];
    __builtin_amdgcn_s_setprio(1);
#pragma unroll
    for (int nf = 0; nf < 4; ++nf) {
      const char* kb = Kc + (nf * 16 + r16) * 128;
      const bf16x8 b0 = *reinterpret_cast<const bf16x8*>(kb + ((g ^ (r16 & 7)) << 4));
      const bf16x8 b1 = *reinterpret_cast<const bf16x8*>(kb + (((4 + g) ^ (r16 & 7)) << 4));
      f32x4 z = (f32x4){0.f, 0.f, 0.f, 0.f};
      z = __builtin_amdgcn_mfma_f32_16x16x32_bf16(b0, aq0, z, 0, 0, 0);
      z = __builtin_amdgcn_mfma_f32_16x16x32_bf16(b1, aq1, z, 0, 0, 0);
      s[nf] = z;
    }
    __builtin_amdgcn_s_setprio(0);

    bf16x8 pa0, pa1;
    soft_side(s, lrun, it == qt, qbase - it * 64, g, r16, pa0, pa1);

    __builtin_amdgcn_s_setprio(1);
#pragma unroll
    for (int nf = 0; nf < 4; ++nf) {
      const char* vb = Vc + (nf * 16 + r16) * 128;
      const bf16x8 v0 = *reinterpret_cast<const bf16x8*>(vb + ((g ^ (r16 & 7)) << 4));
      const bf16x8 v1 = *reinterpret_cast<const bf16x8*>(vb + (((4 + g) ^ (r16 & 7)) << 4));
      oacc[nf] = __builtin_amdgcn_mfma_f32_16x16x32_bf16(pa0, v0, oacc[nf], 0, 0, 0);
      oacc[nf] = __builtin_amdgcn_mfma_f32_16x16x32_bf16(pa1, v1, oacc[nf], 0, 0, 0);
    }
    __builtin_amdgcn_s_setprio(0);
    __syncthreads();
  }

  lrun += __shfl_xor(lrun, 16, 64);
  lrun += __shfl_xor(lrun, 32, 64);
  const float inv = 1.f / lrun;
  float invq[4];
#pragma unroll
  for (int rr = 0; rr < 4; ++rr) invq[rr] = __shfl(inv, 4 * g + rr, 64);
  const int b = bh >> 4, h = bh & 15;
#pragma unroll
  for (int nf = 0; nf < 4; ++nf) {
    const int hd = nf * 16 + r16;
#pragma unroll
    for (int rr = 0; rr < 4; ++rr) {
      const int tt = qbase + g * 4 + rr;
      o[((long)b * T_ + tt) * D_ + h * HD_ + hd] = (__bf16)(oacc[nf][rr] * invq[rr]);
    }
  }
}

// ---------------------------------------------------------------- launcher
extern "C" void kernel_launch(void* const* d_in, const int* in_sizes, int n_in,
                              void* d_out, int out_size, void* d_ws, size_t ws_size,
                              hipStream_t stream) {
  (void)in_sizes; (void)n_in; (void)out_size; (void)ws_size;
  const float* x     = (const float*)d_in[0];
  const float* Wqkv  = (const float*)d_in[1];
  const float* bqkv  = (const float*)d_in[2];
  const float* Wproj = (const float*)d_in[3];
  const float* bproj = (const float*)d_in[4];
  float* out = (float*)d_out;

  const long MT = (long)B_ * T_;          // 8192
  __bf16* xb     = (__bf16*)d_ws;                    // [8192][1024]
  __bf16* wqkvt  = xb + MT * D_;                     // [3072][1024]
  __bf16* wprojt = wqkvt + (long)3 * D_ * D_;        // [1024][1024]
  __bf16* qkvb   = wprojt + (long)D_ * D_;           // q,k: [2][B][H][T][64]
  __bf16* vtb    = qkvb + (long)2 * B_ * H_ * T_ * HD_;  // [B][H][64][T]
  __bf16* attno  = vtb + (long)B_ * H_ * HD_ * T_;   // [8192][1024]

  k_cvt_f32_bf16<<<2048, 256, 0, stream>>>(x, xb, (int)(MT * D_ / 4));
  k_transpose_bf16<float><<<dim3(48, 16, 1), 256, 0, stream>>>(Wqkv, wqkvt, D_, 3 * D_, 0, 0);
  k_transpose_bf16<float><<<dim3(16, 16, 1), 256, 0, stream>>>(Wproj, wprojt, D_, D_, 0, 0);
  k_gemm_qkv256<<<dim3(24, 32), 512, 0, stream>>>(xb, wqkvt, bqkv, qkvb, vtb);
  k_attn<<<dim3(64, 32), 256, 0, stream>>>(
      qkvb, qkvb + (long)B_ * H_ * T_ * HD_, vtb, attno);
  k_gemm_proj<<<dim3(8, 64), 256, 0, stream>>>(attno, wprojt, bproj, out, 8192, 1024, 1024);
}